// Round 10
// baseline (412.648 us; speedup 1.0000x reference)
//
#include <hip/hip_runtime.h>
#include <math.h>

#define NPGN 61
#define NGRAPH 128
#define NNODES (NPGN*NGRAPH)   // 7808
#define EPG 3660               // 61*60 edges per graph

typedef float float4v __attribute__((ext_vector_type(4)));
typedef short bf16x8 __attribute__((ext_vector_type(8)));
typedef unsigned short u16;

__device__ __forceinline__ u16 f2bf(float v){
  union { float f; unsigned u; } x; x.f = v;
  unsigned r = (x.u + 0x7FFFu + ((x.u >> 16) & 1u)) >> 16;
  return (u16)r;
}
__device__ __forceinline__ float bf2f(unsigned u){
  union { unsigned u; float f; } x; x.u = u << 16;
  return x.f;
}

// ------- fused prep: weight re-layouts + lw0 transpose + accs zeroing -------
// blocks >= 534 zero stat1p + y0pre + counter pad (20736 floats, 81 blocks)
__global__ __launch_bounds__(256) void k_prep(const float* __restrict__ w0,
    const float* __restrict__ w1, const float* __restrict__ w2,
    const float* __restrict__ gw0, const float* __restrict__ gw1, const float* __restrict__ gw2,
    const float* __restrict__ lw0,
    float* __restrict__ w0t, u16* __restrict__ w1b, u16* __restrict__ w2b,
    u16* __restrict__ gwt0, u16* __restrict__ gwt1, u16* __restrict__ gwt2,
    u16* __restrict__ lw0t, float* __restrict__ accs){
  __shared__ __align__(16) u16 tile[32*132];
  int b = blockIdx.x, tid = threadIdx.x;
  if (b >= 534){                       // replaces hipMemsetAsync
    int idx = (b - 534)*256 + tid;
    if (idx < 20736) accs[idx] = 0.f;  // stat1p(4096)+y0pre(16384)+cnt pad(256)
    return;
  }
  if (b < 290){
    int idx = b*256 + tid;
    if (idx < 20480){
      int f = idx / 320, r = idx - f*320;
      int kk = r >> 6, c = r & 63;
      w1b[idx] = f2bf(w1[f*320 + c*5 + kk]);
    } else if (idx < 32768){
      int j = idx - 20480; w2b[j] = f2bf(w2[j]);
    } else if (idx < 40960){
      int j = idx - 32768; int jj = j >> 6, k = j & 63; gwt0[j] = f2bf(gw0[k*128 + jj]);
    } else if (idx < 57344){
      int j = idx - 40960; int jj = j >> 7, k = j & 127; gwt1[j] = f2bf(gw1[k*128 + jj]);
    } else if (idx < 73728){
      int j = idx - 57344; int jj = j >> 7, k = j & 127; gwt2[j] = f2bf(gw2[k*128 + jj]);
    } else if (idx < 74176){
      int j = idx - 73728; int k = j >> 6, f = j & 63; w0t[j] = w0[f*7 + k];
    }
  } else {
    int bb = b - 290;
    int i = bb >> 2, oq = bb & 3;      // o-chunk of 32
    for (int idx = tid; idx < 4096; idx += 256){
      int k = idx >> 5, ol = idx & 31;
      tile[ol*132 + k] = f2bf(lw0[((size_t)i*128 + k)*128 + oq*32 + ol]);
    }
    __syncthreads();
    unsigned* dst = (unsigned*)lw0t;
    for (int idx = tid; idx < 2048; idx += 256){
      int ol = idx >> 6, kw = idx & 63;
      unsigned v = (unsigned)tile[ol*132 + 2*kw] | ((unsigned)tile[ol*132 + 2*kw + 1] << 16);
      dst[((size_t)i*128 + oq*32 + ol)*64 + kw] = v;
    }
  }
}

// ---------------- fused conv stack, 4 nodes in PARALLEL, 4 barriers ---------
// unchanged from r8 (44.4 us, passing)
#define A0T_STR 72   // u16 units (144 B)
#define C1_STR 24    // u16 units (48 B)
#define NB 4
__global__ __launch_bounds__(256) void k_conv(const float* __restrict__ x,
    const float* __restrict__ w0t, const float* __restrict__ b0,
    const u16* __restrict__ w1b, const float* __restrict__ b1,
    const u16* __restrict__ w2b, const float* __restrict__ b2,
    float* __restrict__ h0, float* __restrict__ stat1p){
  int w = threadIdx.x >> 6, lane = threadIdx.x & 63;
  int tid = threadIdx.x;
  int q = lane >> 4, r16 = lane & 15;
  __shared__ __align__(16) float xs[NB][160];            // 2560 B
  __shared__ __align__(16) u16 a0t[NB][36*A0T_STR];      // 20736 B
  __shared__ __align__(16) u16 c1s[NB][64*C1_STR];       // 12288 B
  __shared__ __align__(16) u16 a1k[NB][208];             // 1664 B

  {
    const float* xb = x + (size_t)blockIdx.x*NB*160;
    float* xsf = &xs[0][0];
    #pragma unroll
    for (int idx = tid; idx < NB*160; idx += 256) xsf[idx] = xb[idx];
  }

  bf16x8 wf1[10], wf2[6];
  #pragma unroll
  for (int ks = 0; ks < 10; ks++)
    wf1[ks] = *(const bf16x8*)(w1b + (16*w + r16)*320 + ks*32 + q*8);
  #pragma unroll
  for (int ks = 0; ks < 6; ks++)
    wf2[ks] = *(const bf16x8*)(w2b + (16*w + r16)*192 + ks*32 + q*8);
  float4 b1v = *(const float4*)(b1 + 16*w + 4*q);
  float4 b2v = *(const float4*)(b2 + 16*w + 4*q);

  float w0r[7];
  #pragma unroll
  for (int k = 0; k < 7; k++) w0r[k] = w0t[k*64 + lane];
  float b0f = b0[lane];

  #pragma unroll
  for (int i2 = 0; i2 < 6; i2++){
    int rp = (i2 < 2) ? i2 : 22 + i2;
    a0t[w][rp*A0T_STR + lane] = 0;
  }
  __syncthreads();   // B0: xs + pads ready

  for (int j = w; j < 44; j += 4){
    int n = j / 11, qp = j - n*11;
    const float* xsp = &xs[n][0];
    float win[20];
    #pragma unroll
    for (int jj = 0; jj < 20; jj++) win[jj] = xsp[14*qp + jj];
    float m0, m1;
    #pragma unroll
    for (int r = 0; r < 7; r++){
      float s = w0r[0]*win[r];
      #pragma unroll
      for (int k = 1; k < 7; k++) s += w0r[k]*win[r+k];
      m0 = r ? fmaxf(m0, s) : s;
    }
    #pragma unroll
    for (int r = 7; r < 14; r++){
      float s = w0r[0]*win[r];
      #pragma unroll
      for (int k = 1; k < 7; k++) s += w0r[k]*win[r+k];
      m1 = (r > 7) ? fmaxf(m1, s) : s;
    }
    a0t[n][(2 + 2*qp)*A0T_STR + lane] = f2bf(fmaxf(m0 + b0f, 0.f));
    a0t[n][(3 + 2*qp)*A0T_STR + lane] = f2bf(fmaxf(m1 + b0f, 0.f));
  }
  __syncthreads();   // B1: all a0t complete

  #pragma unroll 1
  for (int n = 0; n < NB; n++){
    float4v acc0 = {0.f,0.f,0.f,0.f}, acc1 = {0.f,0.f,0.f,0.f};
    #pragma unroll
    for (int ks = 0; ks < 10; ks++){
      int kk = ks >> 1;
      int cbase = (ks & 1)*32 + q*8;
      bf16x8 bv0 = *(const bf16x8*)(&a0t[n][(r16 + kk)*A0T_STR + cbase]);
      bf16x8 bv1 = *(const bf16x8*)(&a0t[n][(r16 + 16 + kk)*A0T_STR + cbase]);
      acc0 = __builtin_amdgcn_mfma_f32_16x16x32_bf16(wf1[ks], bv0, acc0, 0, 0, 0);
      acc1 = __builtin_amdgcn_mfma_f32_16x16x32_bf16(wf1[ks], bv1, acc1, 0, 0, 0);
    }
    #pragma unroll
    for (int reg = 0; reg < 4; reg++){
      int m = 16*w + q*4 + reg;
      float bv_ = ((const float*)&b1v)[reg];
      c1s[n][m*C1_STR + r16] = f2bf(fmaxf(acc0[reg] + bv_, 0.f));
      if (r16 <= 4)
        c1s[n][m*C1_STR + 16 + r16] = f2bf(fmaxf(acc1[reg] + bv_, 0.f));
    }
  }
  __syncthreads();   // B2: all c1s complete

  {
    const u16* c1 = &c1s[w][0];
    bf16x8 f0 = *(const bf16x8*)(c1 + lane*C1_STR);
    bf16x8 f1 = *(const bf16x8*)(c1 + lane*C1_STR + 8);
    bf16x8 f2 = *(const bf16x8*)(c1 + lane*C1_STR + 16);
    float v[24];
    #pragma unroll
    for (int j = 0; j < 8; j++){
      v[j]    = bf2f((u16)f0[j]);
      v[8+j]  = bf2f((u16)f1[j]);
      v[16+j] = bf2f((u16)f2[j]);
    }
    #pragma unroll
    for (int t = 0; t < 3; t++){
      float m = v[t*7];
      #pragma unroll
      for (int r = 1; r < 7; r++) m = fmaxf(m, v[t*7+r]);
      a1k[w][lane*3 + t] = f2bf(m);
    }
  }
  __syncthreads();   // B3: a1k ready

  float4v sacc = {0.f,0.f,0.f,0.f}, qacc = {0.f,0.f,0.f,0.f};
  #pragma unroll 1
  for (int n = 0; n < NB; n++){
    float4v acc2 = {0.f,0.f,0.f,0.f};
    #pragma unroll
    for (int ks = 0; ks < 6; ks++){
      bf16x8 bs = *(const bf16x8*)(&a1k[n][ks*32 + q*8]);
      acc2 = __builtin_amdgcn_mfma_f32_16x16x32_bf16(wf2[ks], bs, acc2, 0, 0, 0);
    }
    if (r16 == 0){
      int nn = blockIdx.x*NB + n;
      #pragma unroll
      for (int reg = 0; reg < 4; reg++){
        int f = 16*w + 4*q + reg;
        float v = acc2[reg] + ((const float*)&b2v)[reg];
        h0[(size_t)nn*64 + f] = v;
        sacc[reg] += v;
        qacc[reg] += v*v;
      }
    }
  }

  if (r16 == 0){
    int bkt = blockIdx.x & 31;
    #pragma unroll
    for (int reg = 0; reg < 4; reg++){
      int f = 16*w + 4*q + reg;
      atomicAdd(&stat1p[bkt*128 + f], sacc[reg]);
      atomicAdd(&stat1p[bkt*128 + 64 + f], qacc[reg]);
    }
  }
}

// ---------------- fused GNN: edge-tanh head + 3 MFMA layers + bn2 partials --
// unchanged from r8
#define EW_STR 72
#define HS_STR 136
#define HWT_STR 72
__global__ __launch_bounds__(512) void k_gnn(const float* __restrict__ h0,
    const float* __restrict__ stat1p,
    const float* __restrict__ bn1g, const float* __restrict__ bn1b,
    const u16* __restrict__ gwt0, const float* __restrict__ gb0,
    const u16* __restrict__ gwt1, const float* __restrict__ gb1,
    const u16* __restrict__ gwt2, const float* __restrict__ gb2,
    const float* __restrict__ ef, const float* __restrict__ eww,
    const float* __restrict__ ewb, float* __restrict__ out2,
    u16* __restrict__ hB, float* __restrict__ stat2p){
  int g = blockIdx.x, tid = threadIdx.x;
  int w = tid >> 6, lane = tid & 63, q = lane >> 4, r16 = lane & 15;
  int dt = w & 3, jh = w >> 2;
  __shared__ u16 hs[64*HS_STR];
  __shared__ u16 hwT[128*HWT_STR];
  __shared__ u16 ewl[64*EW_STR];
  __shared__ float bsc[64], bsh[64];
  __shared__ float st2[256];

  bf16x8 af0[2], af1[4], af2[4];
  #pragma unroll
  for (int ks = 0; ks < 2; ks++)
    af0[ks] = *(const bf16x8*)(gwt0 + (16*w + r16)*64 + ks*32 + q*8);
  #pragma unroll
  for (int ks = 0; ks < 4; ks++)
    af1[ks] = *(const bf16x8*)(gwt1 + (16*w + r16)*128 + ks*32 + q*8);
  #pragma unroll
  for (int ks = 0; ks < 4; ks++)
    af2[ks] = *(const bf16x8*)(gwt2 + (16*w + r16)*128 + ks*32 + q*8);
  float4 b40 = *(const float4*)(gb0 + 16*w + 4*q);
  float4 b41 = *(const float4*)(gb1 + 16*w + 4*q);
  float4 b42 = *(const float4*)(gb2 + 16*w + 4*q);

  if (tid < 64){
    float s = 0.f, s2 = 0.f;
    #pragma unroll
    for (int r = 0; r < 32; r++){
      s  += stat1p[r*128 + tid];
      s2 += stat1p[r*128 + 64 + tid];
    }
    float m = s*(1.f/NNODES), v = s2*(1.f/NNODES) - m*m;
    float sc = rsqrtf(v + 1e-5f)*bn1g[tid];
    bsc[tid] = sc; bsh[tid] = bn1b[tid] - m*sc;
  }
  if (tid < 256) st2[tid] = 0.f;
  {
    unsigned* td = (unsigned*)ewl;
    for (int idx = tid; idx < 64*EW_STR/2; idx += 512) td[idx] = 0;
  }
  {
    unsigned* hsd = (unsigned*)hs;
    for (int idx = tid; idx < 3*(HS_STR/2); idx += 512){
      int rr = 61 + idx/(HS_STR/2), cc = idx%(HS_STR/2);
      hsd[rr*(HS_STR/2) + cc] = 0;
    }
  }
  __syncthreads();

  {
    float v0 = eww[0], v1 = eww[1], v2 = eww[2], bb = ewb[0];
    const float* efg = ef + (size_t)g*EPG*3;
    for (int idx = tid; idx < EPG; idx += 512){
      const float* p = efg + idx*3;
      float v = tanhf(p[0]*v0 + p[1]*v1 + p[2]*v2 + bb);
      int s = idx/60, r = idx - s*60;
      int d = r + (r >= s ? 1 : 0);
      ewl[d*EW_STR + s] = f2bf(v);
      out2[(size_t)idx*128 + g] = v;
    }
  }
  {
    unsigned* hsd = (unsigned*)hs;
    for (int idx = tid; idx < 61*32; idx += 512){
      int i = idx >> 5, kw = idx & 31;
      float2 hv = *(const float2*)(h0 + ((size_t)g*61 + i)*64 + kw*2);
      int k0 = kw*2;
      float a = hv.x*bsc[k0] + bsh[k0];
      float b = hv.y*bsc[k0+1] + bsh[k0+1];
      hsd[i*(HS_STR/2) + kw] = (unsigned)f2bf(a) | ((unsigned)f2bf(b) << 16);
    }
  }
  __syncthreads();
  bf16x8 ewf[2];
  #pragma unroll
  for (int ks = 0; ks < 2; ks++)
    ewf[ks] = *(const bf16x8*)(ewl + (16*dt + r16)*EW_STR + ks*32 + q*8);

  // layer 0
  #pragma unroll
  for (int nt = 0; nt < 4; nt++){
    float4v acc = {b40.x, b40.y, b40.z, b40.w};
    #pragma unroll
    for (int ks = 0; ks < 2; ks++){
      bf16x8 bv = *(const bf16x8*)(hs + (nt*16 + r16)*HS_STR + ks*32 + q*8);
      acc = __builtin_amdgcn_mfma_f32_16x16x32_bf16(af0[ks], bv, acc, 0, 0, 0);
    }
    #pragma unroll
    for (int r = 0; r < 4; r++)
      hwT[(16*w + 4*q + r)*HWT_STR + nt*16 + r16] = f2bf(acc[r]);
  }
  __syncthreads();
  #pragma unroll
  for (int nt = 0; nt < 4; nt++){
    int j = (jh*4 + nt)*16;
    float4v acc = {0.f,0.f,0.f,0.f};
    #pragma unroll
    for (int ks = 0; ks < 2; ks++){
      bf16x8 bv = *(const bf16x8*)(hwT + (j + r16)*HWT_STR + ks*32 + q*8);
      acc = __builtin_amdgcn_mfma_f32_16x16x32_bf16(ewf[ks], bv, acc, 0, 0, 0);
    }
    #pragma unroll
    for (int r = 0; r < 4; r++){
      int d = 16*dt + 4*q + r;
      hs[d*HS_STR + j + r16] = f2bf(fmaxf(acc[r], 0.f));
    }
  }
  __syncthreads();

  // layer 1
  #pragma unroll
  for (int nt = 0; nt < 4; nt++){
    float4v acc = {b41.x, b41.y, b41.z, b41.w};
    #pragma unroll
    for (int ks = 0; ks < 4; ks++){
      bf16x8 bv = *(const bf16x8*)(hs + (nt*16 + r16)*HS_STR + ks*32 + q*8);
      acc = __builtin_amdgcn_mfma_f32_16x16x32_bf16(af1[ks], bv, acc, 0, 0, 0);
    }
    #pragma unroll
    for (int r = 0; r < 4; r++)
      hwT[(16*w + 4*q + r)*HWT_STR + nt*16 + r16] = f2bf(acc[r]);
  }
  __syncthreads();
  #pragma unroll
  for (int nt = 0; nt < 4; nt++){
    int j = (jh*4 + nt)*16;
    float4v acc = {0.f,0.f,0.f,0.f};
    #pragma unroll
    for (int ks = 0; ks < 2; ks++){
      bf16x8 bv = *(const bf16x8*)(hwT + (j + r16)*HWT_STR + ks*32 + q*8);
      acc = __builtin_amdgcn_mfma_f32_16x16x32_bf16(ewf[ks], bv, acc, 0, 0, 0);
    }
    #pragma unroll
    for (int r = 0; r < 4; r++){
      int d = 16*dt + 4*q + r;
      hs[d*HS_STR + j + r16] = f2bf(fmaxf(acc[r], 0.f));
    }
  }
  __syncthreads();

  // layer 2 (+ bn2 partial tail)
  #pragma unroll
  for (int nt = 0; nt < 4; nt++){
    float4v acc = {b42.x, b42.y, b42.z, b42.w};
    #pragma unroll
    for (int ks = 0; ks < 4; ks++){
      bf16x8 bv = *(const bf16x8*)(hs + (nt*16 + r16)*HS_STR + ks*32 + q*8);
      acc = __builtin_amdgcn_mfma_f32_16x16x32_bf16(af2[ks], bv, acc, 0, 0, 0);
    }
    #pragma unroll
    for (int r = 0; r < 4; r++)
      hwT[(16*w + 4*q + r)*HWT_STR + nt*16 + r16] = f2bf(acc[r]);
  }
  __syncthreads();
  #pragma unroll
  for (int nt = 0; nt < 4; nt++){
    int j = (jh*4 + nt)*16;
    float4v acc = {0.f,0.f,0.f,0.f};
    #pragma unroll
    for (int ks = 0; ks < 2; ks++){
      bf16x8 bv = *(const bf16x8*)(hwT + (j + r16)*HWT_STR + ks*32 + q*8);
      acc = __builtin_amdgcn_mfma_f32_16x16x32_bf16(ewf[ks], bv, acc, 0, 0, 0);
    }
    float cs = 0.f, cq = 0.f;
    #pragma unroll
    for (int r = 0; r < 4; r++){
      int d = 16*dt + 4*q + r;
      if (d < 61){
        float v = acc[r];
        hB[((size_t)g*61 + d)*128 + j + r16] = f2bf(v);
        cs += v; cq += v*v;
      }
    }
    int col = j + r16;
    atomicAdd(&st2[col], cs);
    atomicAdd(&st2[128 + col], cq);
  }
  __syncthreads();
  if (tid < 256) stat2p[(size_t)tid*128 + g] = st2[tid];
}

// ------ fused lin0 (register K-accum, 4x fewer atomics) + last-block MLP ----
// 64 blocks x 256 threads; block (ig, sub) accumulates i = ig*4+t (t<4) in
// registers, ONE atomic per output at end (262K total vs 1M). Last block to
// finish (device counter) runs the mlp1 epilogue for all graphs -- deadlock-
// free without co-residency assumptions.
#define AS_STR 136
__global__ __launch_bounds__(256) void k_mlp01(const u16* __restrict__ hB,
    const float* __restrict__ stat2p,
    const float* __restrict__ bn2g, const float* __restrict__ bn2b,
    const u16* __restrict__ lw0t, float* __restrict__ y0pre,
    unsigned* __restrict__ cnt,
    const float* __restrict__ lb0, const float* __restrict__ W1,
    const float* __restrict__ lb1, const float* __restrict__ W2,
    const float* __restrict__ lb2, float* __restrict__ out){
  int bi = blockIdx.x; int ig = bi >> 2, sub = bi & 3;
  int oh = sub & 1, gh = sub >> 1;
  int tid = threadIdx.x, w = tid >> 6, lane = tid & 63, q = lane >> 4, r16 = lane & 15;
  __shared__ u16 As[64*AS_STR];
  __shared__ float sc2[128], sh2[128];
  __shared__ float y0[2][128], y1[2][128], red[2][128];
  __shared__ unsigned sflag;

  if (tid < 128){
    float4v sa = {0,0,0,0}, sb = {0,0,0,0};
    #pragma unroll
    for (int r = 0; r < 32; r++){
      sa += *(const float4v*)(stat2p + (size_t)tid*128 + r*4);
      sb += *(const float4v*)(stat2p + (size_t)(128 + tid)*128 + r*4);
    }
    float s = sa[0]+sa[1]+sa[2]+sa[3], s2 = sb[0]+sb[1]+sb[2]+sb[3];
    float m = s*(1.f/NNODES), v = s2*(1.f/NNODES) - m*m;
    float sc = rsqrtf(v + 1e-5f)*bn2g[tid];
    sc2[tid] = sc; sh2[tid] = bn2b[tid] - m*sc;
  }

  float4v acc[4];
  #pragma unroll
  for (int nt = 0; nt < 4; nt++) acc[nt] = (float4v){0.f,0.f,0.f,0.f};

  #pragma unroll 1
  for (int t = 0; t < 4; t++){
    int i = ig*4 + t;
    __syncthreads();   // As free (also covers sc2 on t=0)
    if (i < 61){
      const unsigned* hbd = (const unsigned*)hB;
      unsigned* asd = (unsigned*)As;
      for (int idx = tid; idx < 4096; idx += 256){
        int gg = gh*64 + (idx >> 6), kw = idx & 63;
        unsigned pv = hbd[((size_t)gg*61 + i)*64 + kw];
        int k0 = kw*2;
        float a = bf2f(pv & 0xffffu)*sc2[k0] + sh2[k0];
        float b = bf2f(pv >> 16)*sc2[k0+1] + sh2[k0+1];
        asd[(idx >> 6)*(AS_STR/2) + kw] = (unsigned)f2bf(a) | ((unsigned)f2bf(b) << 16);
      }
    }
    __syncthreads();
    if (i < 61){
      const u16* wbase = lw0t + ((size_t)i*128 + oh*64)*128;
      bf16x8 af[4];
      #pragma unroll
      for (int ks = 0; ks < 4; ks++)
        af[ks] = *(const bf16x8*)(As + (16*w + r16)*AS_STR + ks*32 + q*8);
      #pragma unroll
      for (int nt = 0; nt < 4; nt++){
        #pragma unroll
        for (int ks = 0; ks < 4; ks++){
          bf16x8 bv = *(const bf16x8*)(wbase + (size_t)(nt*16 + r16)*128 + ks*32 + q*8);
          acc[nt] = __builtin_amdgcn_mfma_f32_16x16x32_bf16(af[ks], bv, acc[nt], 0, 0, 0);
        }
      }
    }
  }

  // one atomic per output element (was 4)
  #pragma unroll
  for (int nt = 0; nt < 4; nt++){
    #pragma unroll
    for (int r = 0; r < 4; r++){
      int g = gh*64 + 16*w + 4*q + r;
      atomicAdd(&y0pre[(size_t)g*128 + oh*64 + nt*16 + r16], acc[nt][r]);
    }
  }

  // last-block gate
  __threadfence();
  __syncthreads();
  if (tid == 0) sflag = atomicAdd(cnt, 1u);
  __syncthreads();
  if (sflag != 63u) return;

  // ---- mlp1 epilogue (last block only): 2 graphs in parallel, 64 iters ----
  int sg = tid >> 7, o = tid & 127;
  for (int g = sg; g < NGRAPH; g += 2){
    float yv = atomicAdd(&y0pre[(size_t)g*128 + o], 0.f);  // coherent load
    y0[sg][o] = fmaxf(yv + lb0[o], 0.f);
    __syncthreads();
    float a = lb1[o];
    #pragma unroll 8
    for (int k = 0; k < 128; k++) a += y0[sg][k]*W1[k*128 + o];
    y1[sg][o] = fmaxf(a, 0.f);
    __syncthreads();
    int c = o & 3, kb = o >> 2;
    float a2 = 0.f;
    #pragma unroll
    for (int j = 0; j < 4; j++){
      int k = kb + 32*j;
      a2 += y1[sg][k]*W2[k*4 + c];
    }
    red[sg][o] = a2;
    __syncthreads();
    #pragma unroll
    for (int off = 64; off >= 4; off >>= 1){
      if (o < off) red[sg][o] += red[sg][o + off];
      __syncthreads();
    }
    if (o == 0){
      float v0 = red[sg][0]+lb2[0], v1 = red[sg][1]+lb2[1];
      float v2 = red[sg][2]+lb2[2], v3 = red[sg][3]+lb2[3];
      float m = fmaxf(fmaxf(v0,v1), fmaxf(v2,v3));
      float lse = m + logf(expf(v0-m)+expf(v1-m)+expf(v2-m)+expf(v3-m));
      out[g*4+0]=v0-lse; out[g*4+1]=v1-lse; out[g*4+2]=v2-lse; out[g*4+3]=v3-lse;
    }
    __syncthreads();   // before reusing y0/red
  }
}

extern "C" void kernel_launch(void* const* d_in, const int* in_sizes, int n_in,
                              void* d_out, int out_size, void* d_ws, size_t ws_size,
                              hipStream_t stream){
  const float* x    = (const float*)d_in[0];
  const float* ef   = (const float*)d_in[3];
  const float* cw0  = (const float*)d_in[4];
  const float* cb0  = (const float*)d_in[5];
  const float* cw1  = (const float*)d_in[6];
  const float* cb1  = (const float*)d_in[7];
  const float* cw2  = (const float*)d_in[8];
  const float* cb2  = (const float*)d_in[9];
  const float* bn1g = (const float*)d_in[10];
  const float* bn1b = (const float*)d_in[11];
  const float* gw0  = (const float*)d_in[12];
  const float* gb0  = (const float*)d_in[13];
  const float* gw1  = (const float*)d_in[14];
  const float* gb1  = (const float*)d_in[15];
  const float* gw2  = (const float*)d_in[16];
  const float* gb2  = (const float*)d_in[17];
  const float* bn2g = (const float*)d_in[18];
  const float* bn2b = (const float*)d_in[19];
  const float* lw0  = (const float*)d_in[20];
  const float* lb0  = (const float*)d_in[21];
  const float* lw1  = (const float*)d_in[22];
  const float* lb1  = (const float*)d_in[23];
  const float* lw2  = (const float*)d_in[24];
  const float* lb2  = (const float*)d_in[25];
  const float* eww  = (const float*)d_in[26];
  const float* ewb  = (const float*)d_in[27];
  float* out = (float*)d_out;

  float* ws   = (float*)d_ws;
  float* w1s  = ws;               // 10240 f
  float* w2s  = w1s + 10240;      // 6144 f
  float* w0t  = w2s + 6144;       // 448 f
  float* gws0 = w0t + 448;        // 4096 f
  float* gws1 = gws0 + 4096;      // 8192 f
  float* gws2 = gws1 + 8192;      // 8192 f
  float* h0   = gws2 + 8192;      // 499712 f (7808*64 f32)
  float* hBs  = h0 + 499712;      // 499712 f (7808*128 u16)
  float* lw0s = hBs + 499712;     // 499712 f (61*128*128 u16)
  float* accs = lw0s + 499712;    // stat1p(4096)|y0pre(16384)|cnt pad(256)|stat2p(32768)

  u16* w1b    = (u16*)w1s;
  u16* w2b    = (u16*)w2s;
  u16* gwt0   = (u16*)gws0;
  u16* gwt1   = (u16*)gws1;
  u16* gwt2   = (u16*)gws2;
  u16* hB     = (u16*)hBs;
  u16* lw0t   = (u16*)lw0s;
  float* stat1p = accs;             // 32 buckets x 128
  float* y0pre  = accs + 4096;      // 128 x 128
  unsigned* cnt = (unsigned*)(accs + 20480);  // zeroed by prep
  float* stat2p = accs + 20736;     // 256 cols x 128 graphs

  // 4 dispatches (was 6): memset folded into prep; mlp0+mlp1 fused (last-block)
  k_prep <<<615, 256, 0, stream>>>(cw0, cw1, cw2, gw0, gw1, gw2, lw0,
                                   w0t, w1b, w2b, gwt0, gwt1, gwt2, lw0t, accs);
  k_conv <<<NNODES/NB, 256, 0, stream>>>(x, w0t, cb0, w1b, cb1, w2b, cb2, h0, stat1p);
  k_gnn  <<<NGRAPH, 512, 0, stream>>>(h0, stat1p, bn1g, bn1b,
                                      gwt0, gb0, gwt1, gb1, gwt2, gb2,
                                      ef, eww, ewb, out + 512, hB, stat2p);
  k_mlp01<<<64, 256, 0, stream>>>(hB, stat2p, bn2g, bn2b, lw0t, y0pre, cnt,
                                  lb0, lw1, lb1, lw2, lb2, out);
}

// Round 12
// 195.042 us; speedup vs baseline: 2.1157x; 2.1157x over previous
//
#include <hip/hip_runtime.h>
#include <math.h>

#define NPGN 61
#define NGRAPH 128
#define NNODES (NPGN*NGRAPH)   // 7808
#define EPG 3660               // 61*60 edges per graph
#define NCONVB (NNODES/4)      // 1952 conv blocks

typedef float float4v __attribute__((ext_vector_type(4)));
typedef short bf16x8 __attribute__((ext_vector_type(8)));
typedef unsigned short u16;

__device__ __forceinline__ u16 f2bf(float v){
  union { float f; unsigned u; } x; x.f = v;
  unsigned r = (x.u + 0x7FFFu + ((x.u >> 16) & 1u)) >> 16;
  return (u16)r;
}
__device__ __forceinline__ float bf2f(unsigned u){
  union { unsigned u; float f; } x; x.u = u << 16;
  return x.f;
}

// ------- fused prep: weight re-layouts + lw0 transpose + accs zeroing -------
__global__ __launch_bounds__(256) void k_prep(const float* __restrict__ w0,
    const float* __restrict__ w1, const float* __restrict__ w2,
    const float* __restrict__ gw0, const float* __restrict__ gw1, const float* __restrict__ gw2,
    const float* __restrict__ lw0,
    float* __restrict__ w0t, u16* __restrict__ w1b, u16* __restrict__ w2b,
    u16* __restrict__ gwt0, u16* __restrict__ gwt1, u16* __restrict__ gwt2,
    u16* __restrict__ lw0t, float* __restrict__ accs){
  __shared__ __align__(16) u16 tile[32*132];
  int b = blockIdx.x, tid = threadIdx.x;
  if (b >= 534){                       // replaces hipMemsetAsync
    int idx = (b - 534)*256 + tid;
    if (idx < 20480) accs[idx] = 0.f;  // stat1p(4096) + y0pre(16384)
    return;
  }
  if (b < 290){
    int idx = b*256 + tid;
    if (idx < 20480){
      int f = idx / 320, r = idx - f*320;
      int kk = r >> 6, c = r & 63;
      w1b[idx] = f2bf(w1[f*320 + c*5 + kk]);
    } else if (idx < 32768){
      int j = idx - 20480; w2b[j] = f2bf(w2[j]);
    } else if (idx < 40960){
      int j = idx - 32768; int jj = j >> 6, k = j & 63; gwt0[j] = f2bf(gw0[k*128 + jj]);
    } else if (idx < 57344){
      int j = idx - 40960; int jj = j >> 7, k = j & 127; gwt1[j] = f2bf(gw1[k*128 + jj]);
    } else if (idx < 73728){
      int j = idx - 57344; int jj = j >> 7, k = j & 127; gwt2[j] = f2bf(gw2[k*128 + jj]);
    } else if (idx < 74176){
      int j = idx - 73728; int k = j >> 6, f = j & 63; w0t[j] = w0[f*7 + k];
    }
  } else {
    int bb = b - 290;
    int i = bb >> 2, oq = bb & 3;      // o-chunk of 32
    for (int idx = tid; idx < 4096; idx += 256){
      int k = idx >> 5, ol = idx & 31;
      tile[ol*132 + k] = f2bf(lw0[((size_t)i*128 + k)*128 + oq*32 + ol]);
    }
    __syncthreads();
    unsigned* dst = (unsigned*)lw0t;
    for (int idx = tid; idx < 2048; idx += 256){
      int ol = idx >> 6, kw = idx & 63;
      unsigned v = (unsigned)tile[ol*132 + 2*kw] | ((unsigned)tile[ol*132 + 2*kw + 1] << 16);
      dst[((size_t)i*128 + oq*32 + ol)*64 + kw] = v;
    }
  }
}

// ------- fused conv stack (r8, 44 us) + 128 edge-tanh blocks appended -------
// Edge blocks (>=NCONVB) run CONCURRENTLY with conv blocks on idle CU capacity
// (conv occupancy ~25%): compute tanh head, write out2, and store the dense
// bf16 ew matrix (ews[g][64*72], zero diagonal/pad) so k_gnn skips its whole
// edge phase and loads ewf fragments straight from global (L2-hot, 9KB/graph).
#define A0T_STR 72   // u16 units (144 B)
#define C1_STR 24    // u16 units (48 B)
#define NB 4
#define EW_STR 72
__global__ __launch_bounds__(256) void k_conv(const float* __restrict__ x,
    const float* __restrict__ w0t, const float* __restrict__ b0,
    const u16* __restrict__ w1b, const float* __restrict__ b1,
    const u16* __restrict__ w2b, const float* __restrict__ b2,
    float* __restrict__ h0, float* __restrict__ stat1p,
    const float* __restrict__ ef, const float* __restrict__ eww,
    const float* __restrict__ ewb, float* __restrict__ out2,
    u16* __restrict__ ews){
  int tid = threadIdx.x;
  if (blockIdx.x >= NCONVB){
    // ---------------- edge-tanh block (one graph) ----------------
    int g = blockIdx.x - NCONVB;
    u16* eg = ews + (size_t)g*(64*EW_STR);
    for (int idx = tid; idx < 64*EW_STR; idx += 256) eg[idx] = 0;
    __syncthreads();
    float v0 = eww[0], v1 = eww[1], v2 = eww[2], bb = ewb[0];
    const float* efg = ef + (size_t)g*EPG*3;
    for (int idx = tid; idx < EPG; idx += 256){
      const float* p = efg + idx*3;
      float v = tanhf(p[0]*v0 + p[1]*v1 + p[2]*v2 + bb);
      int s = idx/60, r = idx - s*60;
      int d = r + (r >= s ? 1 : 0);
      eg[d*EW_STR + s] = f2bf(v);
      out2[(size_t)idx*128 + g] = v;
    }
    return;
  }

  int w = tid >> 6, lane = tid & 63;
  int q = lane >> 4, r16 = lane & 15;
  __shared__ __align__(16) float xs[NB][160];            // 2560 B
  __shared__ __align__(16) u16 a0t[NB][36*A0T_STR];      // 20736 B
  __shared__ __align__(16) u16 c1s[NB][64*C1_STR];       // 12288 B
  __shared__ __align__(16) u16 a1k[NB][208];             // 1664 B

  {
    const float* xb = x + (size_t)blockIdx.x*NB*160;
    float* xsf = &xs[0][0];
    #pragma unroll
    for (int idx = tid; idx < NB*160; idx += 256) xsf[idx] = xb[idx];
  }

  bf16x8 wf1[10], wf2[6];
  #pragma unroll
  for (int ks = 0; ks < 10; ks++)
    wf1[ks] = *(const bf16x8*)(w1b + (16*w + r16)*320 + ks*32 + q*8);
  #pragma unroll
  for (int ks = 0; ks < 6; ks++)
    wf2[ks] = *(const bf16x8*)(w2b + (16*w + r16)*192 + ks*32 + q*8);
  float4 b1v = *(const float4*)(b1 + 16*w + 4*q);
  float4 b2v = *(const float4*)(b2 + 16*w + 4*q);

  float w0r[7];
  #pragma unroll
  for (int k = 0; k < 7; k++) w0r[k] = w0t[k*64 + lane];
  float b0f = b0[lane];

  #pragma unroll
  for (int i2 = 0; i2 < 6; i2++){
    int rp = (i2 < 2) ? i2 : 22 + i2;
    a0t[w][rp*A0T_STR + lane] = 0;
  }
  __syncthreads();   // B0: xs + pads ready

  for (int j = w; j < 44; j += 4){
    int n = j / 11, qp = j - n*11;
    const float* xsp = &xs[n][0];
    float win[20];
    #pragma unroll
    for (int jj = 0; jj < 20; jj++) win[jj] = xsp[14*qp + jj];
    float m0, m1;
    #pragma unroll
    for (int r = 0; r < 7; r++){
      float s = w0r[0]*win[r];
      #pragma unroll
      for (int k = 1; k < 7; k++) s += w0r[k]*win[r+k];
      m0 = r ? fmaxf(m0, s) : s;
    }
    #pragma unroll
    for (int r = 7; r < 14; r++){
      float s = w0r[0]*win[r];
      #pragma unroll
      for (int k = 1; k < 7; k++) s += w0r[k]*win[r+k];
      m1 = (r > 7) ? fmaxf(m1, s) : s;
    }
    a0t[n][(2 + 2*qp)*A0T_STR + lane] = f2bf(fmaxf(m0 + b0f, 0.f));
    a0t[n][(3 + 2*qp)*A0T_STR + lane] = f2bf(fmaxf(m1 + b0f, 0.f));
  }
  __syncthreads();   // B1: all a0t complete

  #pragma unroll 1
  for (int n = 0; n < NB; n++){
    float4v acc0 = {0.f,0.f,0.f,0.f}, acc1 = {0.f,0.f,0.f,0.f};
    #pragma unroll
    for (int ks = 0; ks < 10; ks++){
      int kk = ks >> 1;
      int cbase = (ks & 1)*32 + q*8;
      bf16x8 bv0 = *(const bf16x8*)(&a0t[n][(r16 + kk)*A0T_STR + cbase]);
      bf16x8 bv1 = *(const bf16x8*)(&a0t[n][(r16 + 16 + kk)*A0T_STR + cbase]);
      acc0 = __builtin_amdgcn_mfma_f32_16x16x32_bf16(wf1[ks], bv0, acc0, 0, 0, 0);
      acc1 = __builtin_amdgcn_mfma_f32_16x16x32_bf16(wf1[ks], bv1, acc1, 0, 0, 0);
    }
    #pragma unroll
    for (int reg = 0; reg < 4; reg++){
      int m = 16*w + q*4 + reg;
      float bv_ = ((const float*)&b1v)[reg];
      c1s[n][m*C1_STR + r16] = f2bf(fmaxf(acc0[reg] + bv_, 0.f));
      if (r16 <= 4)
        c1s[n][m*C1_STR + 16 + r16] = f2bf(fmaxf(acc1[reg] + bv_, 0.f));
    }
  }
  __syncthreads();   // B2: all c1s complete

  {
    const u16* c1 = &c1s[w][0];
    bf16x8 f0 = *(const bf16x8*)(c1 + lane*C1_STR);
    bf16x8 f1 = *(const bf16x8*)(c1 + lane*C1_STR + 8);
    bf16x8 f2 = *(const bf16x8*)(c1 + lane*C1_STR + 16);
    float v[24];
    #pragma unroll
    for (int j = 0; j < 8; j++){
      v[j]    = bf2f((u16)f0[j]);
      v[8+j]  = bf2f((u16)f1[j]);
      v[16+j] = bf2f((u16)f2[j]);
    }
    #pragma unroll
    for (int t = 0; t < 3; t++){
      float m = v[t*7];
      #pragma unroll
      for (int r = 1; r < 7; r++) m = fmaxf(m, v[t*7+r]);
      a1k[w][lane*3 + t] = f2bf(m);
    }
  }
  __syncthreads();   // B3: a1k ready

  float4v sacc = {0.f,0.f,0.f,0.f}, qacc = {0.f,0.f,0.f,0.f};
  #pragma unroll 1
  for (int n = 0; n < NB; n++){
    float4v acc2 = {0.f,0.f,0.f,0.f};
    #pragma unroll
    for (int ks = 0; ks < 6; ks++){
      bf16x8 bs = *(const bf16x8*)(&a1k[n][ks*32 + q*8]);
      acc2 = __builtin_amdgcn_mfma_f32_16x16x32_bf16(wf2[ks], bs, acc2, 0, 0, 0);
    }
    if (r16 == 0){
      int nn = blockIdx.x*NB + n;
      #pragma unroll
      for (int reg = 0; reg < 4; reg++){
        int f = 16*w + 4*q + reg;
        float v = acc2[reg] + ((const float*)&b2v)[reg];
        h0[(size_t)nn*64 + f] = v;
        sacc[reg] += v;
        qacc[reg] += v*v;
      }
    }
  }

  if (r16 == 0){
    int bkt = blockIdx.x & 31;
    #pragma unroll
    for (int reg = 0; reg < 4; reg++){
      int f = 16*w + 4*q + reg;
      atomicAdd(&stat1p[bkt*128 + f], sacc[reg]);
      atomicAdd(&stat1p[bkt*128 + 64 + f], qacc[reg]);
    }
  }
}

// ------- fused GNN: 3 MFMA layers + bn2 partials (edge head precomputed) ----
#define HS_STR 136
#define HWT_STR 72
__global__ __launch_bounds__(512) void k_gnn(const float* __restrict__ h0,
    const float* __restrict__ stat1p,
    const float* __restrict__ bn1g, const float* __restrict__ bn1b,
    const u16* __restrict__ gwt0, const float* __restrict__ gb0,
    const u16* __restrict__ gwt1, const float* __restrict__ gb1,
    const u16* __restrict__ gwt2, const float* __restrict__ gb2,
    const u16* __restrict__ ews,
    u16* __restrict__ hB, float* __restrict__ stat2p){
  int g = blockIdx.x, tid = threadIdx.x;
  int w = tid >> 6, lane = tid & 63, q = lane >> 4, r16 = lane & 15;
  int dt = w & 3, jh = w >> 2;
  __shared__ u16 hs[64*HS_STR];
  __shared__ u16 hwT[128*HWT_STR];
  __shared__ float bsc[64], bsh[64];
  __shared__ float st2[256];

  bf16x8 af0[2], af1[4], af2[4], ewf[2];
  #pragma unroll
  for (int ks = 0; ks < 2; ks++)
    af0[ks] = *(const bf16x8*)(gwt0 + (16*w + r16)*64 + ks*32 + q*8);
  #pragma unroll
  for (int ks = 0; ks < 4; ks++)
    af1[ks] = *(const bf16x8*)(gwt1 + (16*w + r16)*128 + ks*32 + q*8);
  #pragma unroll
  for (int ks = 0; ks < 4; ks++)
    af2[ks] = *(const bf16x8*)(gwt2 + (16*w + r16)*128 + ks*32 + q*8);
  #pragma unroll
  for (int ks = 0; ks < 2; ks++)
    ewf[ks] = *(const bf16x8*)(ews + (size_t)g*(64*EW_STR) + (16*dt + r16)*EW_STR + ks*32 + q*8);
  float4 b40 = *(const float4*)(gb0 + 16*w + 4*q);
  float4 b41 = *(const float4*)(gb1 + 16*w + 4*q);
  float4 b42 = *(const float4*)(gb2 + 16*w + 4*q);

  if (tid < 64){
    float s = 0.f, s2 = 0.f;
    #pragma unroll
    for (int r = 0; r < 32; r++){
      s  += stat1p[r*128 + tid];
      s2 += stat1p[r*128 + 64 + tid];
    }
    float m = s*(1.f/NNODES), v = s2*(1.f/NNODES) - m*m;
    float sc = rsqrtf(v + 1e-5f)*bn1g[tid];
    bsc[tid] = sc; bsh[tid] = bn1b[tid] - m*sc;
  }
  if (tid < 256) st2[tid] = 0.f;
  {
    unsigned* hsd = (unsigned*)hs;
    for (int idx = tid; idx < 3*(HS_STR/2); idx += 512){
      int rr = 61 + idx/(HS_STR/2), cc = idx%(HS_STR/2);
      hsd[rr*(HS_STR/2) + cc] = 0;
    }
  }
  __syncthreads();

  // bn1-normalized node features -> hs
  {
    unsigned* hsd = (unsigned*)hs;
    for (int idx = tid; idx < 61*32; idx += 512){
      int i = idx >> 5, kw = idx & 31;
      float2 hv = *(const float2*)(h0 + ((size_t)g*61 + i)*64 + kw*2);
      int k0 = kw*2;
      float a = hv.x*bsc[k0] + bsh[k0];
      float b = hv.y*bsc[k0+1] + bsh[k0+1];
      hsd[i*(HS_STR/2) + kw] = (unsigned)f2bf(a) | ((unsigned)f2bf(b) << 16);
    }
  }
  __syncthreads();

  // layer 0
  #pragma unroll
  for (int nt = 0; nt < 4; nt++){
    float4v acc = {b40.x, b40.y, b40.z, b40.w};
    #pragma unroll
    for (int ks = 0; ks < 2; ks++){
      bf16x8 bv = *(const bf16x8*)(hs + (nt*16 + r16)*HS_STR + ks*32 + q*8);
      acc = __builtin_amdgcn_mfma_f32_16x16x32_bf16(af0[ks], bv, acc, 0, 0, 0);
    }
    #pragma unroll
    for (int r = 0; r < 4; r++)
      hwT[(16*w + 4*q + r)*HWT_STR + nt*16 + r16] = f2bf(acc[r]);
  }
  __syncthreads();
  #pragma unroll
  for (int nt = 0; nt < 4; nt++){
    int j = (jh*4 + nt)*16;
    float4v acc = {0.f,0.f,0.f,0.f};
    #pragma unroll
    for (int ks = 0; ks < 2; ks++){
      bf16x8 bv = *(const bf16x8*)(hwT + (j + r16)*HWT_STR + ks*32 + q*8);
      acc = __builtin_amdgcn_mfma_f32_16x16x32_bf16(ewf[ks], bv, acc, 0, 0, 0);
    }
    #pragma unroll
    for (int r = 0; r < 4; r++){
      int d = 16*dt + 4*q + r;
      hs[d*HS_STR + j + r16] = f2bf(fmaxf(acc[r], 0.f));
    }
  }
  __syncthreads();

  // layer 1
  #pragma unroll
  for (int nt = 0; nt < 4; nt++){
    float4v acc = {b41.x, b41.y, b41.z, b41.w};
    #pragma unroll
    for (int ks = 0; ks < 4; ks++){
      bf16x8 bv = *(const bf16x8*)(hs + (nt*16 + r16)*HS_STR + ks*32 + q*8);
      acc = __builtin_amdgcn_mfma_f32_16x16x32_bf16(af1[ks], bv, acc, 0, 0, 0);
    }
    #pragma unroll
    for (int r = 0; r < 4; r++)
      hwT[(16*w + 4*q + r)*HWT_STR + nt*16 + r16] = f2bf(acc[r]);
  }
  __syncthreads();
  #pragma unroll
  for (int nt = 0; nt < 4; nt++){
    int j = (jh*4 + nt)*16;
    float4v acc = {0.f,0.f,0.f,0.f};
    #pragma unroll
    for (int ks = 0; ks < 2; ks++){
      bf16x8 bv = *(const bf16x8*)(hwT + (j + r16)*HWT_STR + ks*32 + q*8);
      acc = __builtin_amdgcn_mfma_f32_16x16x32_bf16(ewf[ks], bv, acc, 0, 0, 0);
    }
    #pragma unroll
    for (int r = 0; r < 4; r++){
      int d = 16*dt + 4*q + r;
      hs[d*HS_STR + j + r16] = f2bf(fmaxf(acc[r], 0.f));
    }
  }
  __syncthreads();

  // layer 2 (+ bn2 partial tail)
  #pragma unroll
  for (int nt = 0; nt < 4; nt++){
    float4v acc = {b42.x, b42.y, b42.z, b42.w};
    #pragma unroll
    for (int ks = 0; ks < 4; ks++){
      bf16x8 bv = *(const bf16x8*)(hs + (nt*16 + r16)*HS_STR + ks*32 + q*8);
      acc = __builtin_amdgcn_mfma_f32_16x16x32_bf16(af2[ks], bv, acc, 0, 0, 0);
    }
    #pragma unroll
    for (int r = 0; r < 4; r++)
      hwT[(16*w + 4*q + r)*HWT_STR + nt*16 + r16] = f2bf(acc[r]);
  }
  __syncthreads();
  #pragma unroll
  for (int nt = 0; nt < 4; nt++){
    int j = (jh*4 + nt)*16;
    float4v acc = {0.f,0.f,0.f,0.f};
    #pragma unroll
    for (int ks = 0; ks < 2; ks++){
      bf16x8 bv = *(const bf16x8*)(hwT + (j + r16)*HWT_STR + ks*32 + q*8);
      acc = __builtin_amdgcn_mfma_f32_16x16x32_bf16(ewf[ks], bv, acc, 0, 0, 0);
    }
    float cs = 0.f, cq = 0.f;
    #pragma unroll
    for (int r = 0; r < 4; r++){
      int d = 16*dt + 4*q + r;
      if (d < 61){
        float v = acc[r];
        hB[((size_t)g*61 + d)*128 + j + r16] = f2bf(v);
        cs += v; cq += v*v;
      }
    }
    int col = j + r16;
    atomicAdd(&st2[col], cs);
    atomicAdd(&st2[128 + col], cq);
  }
  __syncthreads();
  if (tid < 256) stat2p[(size_t)tid*128 + g] = st2[tid];
}

// ---------------- lin0 via MFMA, atomic split-K into y0pre (r8) -------------
#define AS_STR 136
__global__ __launch_bounds__(256) void k_mlp0(const u16* __restrict__ hB,
    const float* __restrict__ stat2p,
    const float* __restrict__ bn2g, const float* __restrict__ bn2b,
    const u16* __restrict__ lw0t, float* __restrict__ y0pre){
  int bi = blockIdx.x; int i = bi >> 2, sub = bi & 3;
  int oh = sub & 1, gh = sub >> 1;
  int tid = threadIdx.x, w = tid >> 6, lane = tid & 63, q = lane >> 4, r16 = lane & 15;
  __shared__ u16 As[64*AS_STR];
  __shared__ float sc2[128], sh2[128];
  if (tid < 128){
    float4v sa = {0,0,0,0}, sb = {0,0,0,0};
    #pragma unroll
    for (int r = 0; r < 32; r++){
      sa += *(const float4v*)(stat2p + (size_t)tid*128 + r*4);
      sb += *(const float4v*)(stat2p + (size_t)(128 + tid)*128 + r*4);
    }
    float s = sa[0]+sa[1]+sa[2]+sa[3], s2 = sb[0]+sb[1]+sb[2]+sb[3];
    float m = s*(1.f/NNODES), v = s2*(1.f/NNODES) - m*m;
    float sc = rsqrtf(v + 1e-5f)*bn2g[tid];
    sc2[tid] = sc; sh2[tid] = bn2b[tid] - m*sc;
  }
  __syncthreads();
  {
    const unsigned* hbd = (const unsigned*)hB;
    unsigned* asd = (unsigned*)As;
    for (int idx = tid; idx < 4096; idx += 256){
      int gg = gh*64 + (idx >> 6), kw = idx & 63;
      unsigned pv = hbd[((size_t)gg*61 + i)*64 + kw];
      int k0 = kw*2;
      float a = bf2f(pv & 0xffffu)*sc2[k0] + sh2[k0];
      float b = bf2f(pv >> 16)*sc2[k0+1] + sh2[k0+1];
      asd[(idx >> 6)*(AS_STR/2) + kw] = (unsigned)f2bf(a) | ((unsigned)f2bf(b) << 16);
    }
  }
  __syncthreads();
  const u16* wbase = lw0t + ((size_t)i*128 + oh*64)*128;
  bf16x8 af[4];
  #pragma unroll
  for (int ks = 0; ks < 4; ks++)
    af[ks] = *(const bf16x8*)(As + (16*w + r16)*AS_STR + ks*32 + q*8);
  #pragma unroll
  for (int nt = 0; nt < 4; nt++){
    float4v acc = {0.f,0.f,0.f,0.f};
    #pragma unroll
    for (int ks = 0; ks < 4; ks++){
      bf16x8 bv = *(const bf16x8*)(wbase + (size_t)(nt*16 + r16)*128 + ks*32 + q*8);
      acc = __builtin_amdgcn_mfma_f32_16x16x32_bf16(af[ks], bv, acc, 0, 0, 0);
    }
    #pragma unroll
    for (int r = 0; r < 4; r++){
      int g = gh*64 + 16*w + 4*q + r;
      atomicAdd(&y0pre[(size_t)g*128 + oh*64 + nt*16 + r16], acc[r]);
    }
  }
}

// ---------------- epilogue: bias+relu + lin1 + lin2 + log_softmax -----------
__global__ __launch_bounds__(128) void k_mlp1(const float* __restrict__ y0pre,
    const float* __restrict__ lb0, const float* __restrict__ W1,
    const float* __restrict__ lb1, const float* __restrict__ W2,
    const float* __restrict__ lb2, float* __restrict__ out){
  int g = blockIdx.x, o = threadIdx.x;
  __shared__ float y0[128], y1[128], red[128];
  y0[o] = fmaxf(y0pre[(size_t)g*128 + o] + lb0[o], 0.f);
  __syncthreads();
  float a = lb1[o];
  #pragma unroll 8
  for (int k = 0; k < 128; k++) a += y0[k]*W1[k*128 + o];
  y1[o] = fmaxf(a, 0.f);
  __syncthreads();
  int c = o & 3, kb = o >> 2;
  float a2 = 0.f;
  #pragma unroll
  for (int j = 0; j < 4; j++){
    int k = kb + 32*j;
    a2 += y1[k]*W2[k*4 + c];
  }
  red[o] = a2;
  __syncthreads();
  #pragma unroll
  for (int off = 64; off >= 4; off >>= 1){
    if (o < off) red[o] += red[o + off];
    __syncthreads();
  }
  if (o == 0){
    float v0 = red[0]+lb2[0], v1 = red[1]+lb2[1], v2 = red[2]+lb2[2], v3 = red[3]+lb2[3];
    float m = fmaxf(fmaxf(v0,v1), fmaxf(v2,v3));
    float lse = m + logf(expf(v0-m)+expf(v1-m)+expf(v2-m)+expf(v3-m));
    out[g*4+0]=v0-lse; out[g*4+1]=v1-lse; out[g*4+2]=v2-lse; out[g*4+3]=v3-lse;
  }
}

extern "C" void kernel_launch(void* const* d_in, const int* in_sizes, int n_in,
                              void* d_out, int out_size, void* d_ws, size_t ws_size,
                              hipStream_t stream){
  const float* x    = (const float*)d_in[0];
  const float* ef   = (const float*)d_in[3];
  const float* cw0  = (const float*)d_in[4];
  const float* cb0  = (const float*)d_in[5];
  const float* cw1  = (const float*)d_in[6];
  const float* cb1  = (const float*)d_in[7];
  const float* cw2  = (const float*)d_in[8];
  const float* cb2  = (const float*)d_in[9];
  const float* bn1g = (const float*)d_in[10];
  const float* bn1b = (const float*)d_in[11];
  const float* gw0  = (const float*)d_in[12];
  const float* gb0  = (const float*)d_in[13];
  const float* gw1  = (const float*)d_in[14];
  const float* gb1  = (const float*)d_in[15];
  const float* gw2  = (const float*)d_in[16];
  const float* gb2  = (const float*)d_in[17];
  const float* bn2g = (const float*)d_in[18];
  const float* bn2b = (const float*)d_in[19];
  const float* lw0  = (const float*)d_in[20];
  const float* lb0  = (const float*)d_in[21];
  const float* lw1  = (const float*)d_in[22];
  const float* lb1  = (const float*)d_in[23];
  const float* lw2  = (const float*)d_in[24];
  const float* lb2  = (const float*)d_in[25];
  const float* eww  = (const float*)d_in[26];
  const float* ewb  = (const float*)d_in[27];
  float* out = (float*)d_out;

  float* ws   = (float*)d_ws;
  float* w1s  = ws;               // 10240 f
  float* w2s  = w1s + 10240;      // 6144 f
  float* w0t  = w2s + 6144;       // 448 f
  float* gws0 = w0t + 448;        // 4096 f
  float* gws1 = gws0 + 4096;      // 8192 f
  float* gws2 = gws1 + 8192;      // 8192 f
  float* h0   = gws2 + 8192;      // 499712 f (7808*64 f32)
  float* hBs  = h0 + 499712;      // 499712 f (7808*128 u16)
  float* lw0s = hBs + 499712;     // 499712 f (61*128*128 u16)
  float* accs = lw0s + 499712;    // stat1p(4096)|y0pre(16384)|stat2p(32768)
  float* ewss = accs + 53248;     // 128*4608 u16 = 147456 f

  u16* w1b    = (u16*)w1s;
  u16* w2b    = (u16*)w2s;
  u16* gwt0   = (u16*)gws0;
  u16* gwt1   = (u16*)gws1;
  u16* gwt2   = (u16*)gws2;
  u16* hB     = (u16*)hBs;
  u16* lw0t   = (u16*)lw0s;
  u16* ews    = (u16*)ewss;
  float* stat1p = accs;             // 32 buckets x 128
  float* y0pre  = accs + 4096;      // 128 x 128
  float* stat2p = accs + 20480;     // 256 cols x 128 graphs

  // 5 dispatches: memset folded into prep; edge-tanh folded into conv grid
  k_prep <<<615, 256, 0, stream>>>(cw0, cw1, cw2, gw0, gw1, gw2, lw0,
                                   w0t, w1b, w2b, gwt0, gwt1, gwt2, lw0t, accs);
  k_conv <<<NCONVB + NGRAPH, 256, 0, stream>>>(x, w0t, cb0, w1b, cb1, w2b, cb2,
                                               h0, stat1p, ef, eww, ewb,
                                               out + 512, ews);
  k_gnn  <<<NGRAPH, 512, 0, stream>>>(h0, stat1p, bn1g, bn1b,
                                      gwt0, gb0, gwt1, gb1, gwt2, gb2,
                                      ews, hB, stat2p);
  k_mlp0 <<<NPGN*4, 256, 0, stream>>>(hB, stat2p, bn2g, bn2b, lw0t, y0pre);
  k_mlp1 <<<NGRAPH, 128, 0, stream>>>(y0pre, lb0, lw1, lb1, lw2, lb2, out);
}